// Round 1
// baseline (1053.800 us; speedup 1.0000x reference)
//
#include <hip/hip_runtime.h>
#include <stdint.h>

#define NN 10000
#define DD 256
#define WPR 160            // uint64 words per bitmask row (160*64 = 10240 bits)
#define COLPAD 10240       // padded column-vector length (so bit_agg loads stay in-bounds)
#define FNEG -3.402823466e38f

typedef __attribute__((ext_vector_type(8))) short bf16x8;
typedef __attribute__((ext_vector_type(4))) float f32x4;

static __device__ __forceinline__ unsigned int f2bf(float f) {
    unsigned int u = __float_as_uint(f);
    return (u + 0x7fffu + ((u >> 16) & 1u)) >> 16;   // round-to-nearest-even
}

// ---------- x: f32 -> bf16, plus extract column 0 (fp32) ----------
__global__ __launch_bounds__(256) void convert_x(
    const float* __restrict__ x1, const float* __restrict__ x2,
    unsigned short* __restrict__ xb1, unsigned short* __restrict__ xb2,
    float* __restrict__ c1, float* __restrict__ c2)
{
    const float* x; unsigned short* xb; float* cp;
    if (blockIdx.y == 0) { x = x1; xb = xb1; cp = c1; }
    else                 { x = x2; xb = xb2; cp = c2; }
    int i = (blockIdx.x * 256 + threadIdx.x) * 4;     // grid.x=2500 -> covers 2,560,000 exactly
    float4 v = *(const float4*)(x + i);
    uint2 p;
    p.x = f2bf(v.x) | (f2bf(v.y) << 16);
    p.y = f2bf(v.z) | (f2bf(v.w) << 16);
    *(uint2*)(xb + i) = p;
    if ((i & (DD - 1)) == 0) cp[i >> 8] = v.x;
}

// ---------- ws weights: f32 -> bf16 (layout preserved: W[d][k]) ----------
__global__ __launch_bounds__(256) void convert_w(
    const float* __restrict__ w0, const float* __restrict__ w1,
    const float* __restrict__ w2, const float* __restrict__ w3,
    unsigned short* __restrict__ wb)
{
    const float* w = (blockIdx.y == 0) ? w0 : (blockIdx.y == 1) ? w1
                   : (blockIdx.y == 2) ? w2 : w3;
    unsigned short* o = wb + (size_t)blockIdx.y * DD * DD;
    int i = (blockIdx.x * 256 + threadIdx.x) * 4;     // grid.x=64 -> 65536 exactly
    float4 v = *(const float4*)(w + i);
    uint2 p;
    p.x = f2bf(v.x) | (f2bf(v.y) << 16);
    p.y = f2bf(v.z) | (f2bf(v.w) << 16);
    *(uint2*)(o + i) = p;
}

// ---------- wn row sums: wsum[m][d] = sum_k wn_m[d][k] ----------
__global__ void wn_rowsum(
    const float* __restrict__ w0, const float* __restrict__ w1,
    const float* __restrict__ w2, const float* __restrict__ w3,
    float* __restrict__ wsum)
{
    const float* w = (blockIdx.y == 0) ? w0 : (blockIdx.y == 1) ? w1
                   : (blockIdx.y == 2) ? w2 : w3;
    int d = blockIdx.x, lane = threadIdx.x;           // block = 64
    float s = 0.f;
    for (int k = lane; k < DD; k += 64) s += w[d * DD + k];
    #pragma unroll
    for (int off = 32; off; off >>= 1) s += __shfl_down(s, off);
    if (lane == 0) wsum[blockIdx.y * DD + d] = s;
}

// ---------- fused: read adjacency once -> bitmask + layer-0 aggregate ----------
// MODE 0: masked MAX of vals ; MODE 1: masked SUM of vals
template<int MODE>
__global__ __launch_bounds__(256) void pack_agg(
    const int* __restrict__ adj, const float* __restrict__ vals,
    unsigned long long* __restrict__ bm, float* __restrict__ neigh)
{
    const int row = blockIdx.x;
    const int* __restrict__ arow = adj + (size_t)row * NN;
    unsigned long long* __restrict__ brow = bm + (size_t)row * WPR;
    const int t = threadIdx.x, wv = t >> 6, lane = t & 63;

    float acc = (MODE == 0) ? FNEG : 0.f;
    int any = 0;
    #pragma unroll
    for (int it = 0; it < 10; ++it) {
        int c = it * 1024 + wv * 256 + lane;          // 4 strided columns per thread
        int c1 = c + 64, c2 = c + 128, c3 = c + 192;
        int v0 = (c  < NN) ? arow[c]  : 0;
        int v1 = (c1 < NN) ? arow[c1] : 0;
        int v2 = (c2 < NN) ? arow[c2] : 0;
        int v3 = (c3 < NN) ? arow[c3] : 0;
        float x0 = vals[c], x1 = vals[c1], x2 = vals[c2], x3 = vals[c3]; // COLPAD buffer
        unsigned long long b0 = __ballot(v0 > 0);
        unsigned long long b1 = __ballot(v1 > 0);
        unsigned long long b2 = __ballot(v2 > 0);
        unsigned long long b3 = __ballot(v3 > 0);
        if (lane == 0) {
            int wbase = it * 16 + wv * 4;
            brow[wbase + 0] = b0; brow[wbase + 1] = b1;
            brow[wbase + 2] = b2; brow[wbase + 3] = b3;
        }
        if (MODE == 0) {
            acc = (v0 > 0) ? fmaxf(acc, x0) : acc;
            acc = (v1 > 0) ? fmaxf(acc, x1) : acc;
            acc = (v2 > 0) ? fmaxf(acc, x2) : acc;
            acc = (v3 > 0) ? fmaxf(acc, x3) : acc;
        } else {
            acc += (v0 > 0) ? x0 : 0.f;
            acc += (v1 > 0) ? x1 : 0.f;
            acc += (v2 > 0) ? x2 : 0.f;
            acc += (v3 > 0) ? x3 : 0.f;
        }
        any |= (v0 > 0) | (v1 > 0) | (v2 > 0) | (v3 > 0);
    }
    #pragma unroll
    for (int off = 32; off; off >>= 1) {
        float o = __shfl_down(acc, off);
        acc = (MODE == 0) ? fmaxf(acc, o) : acc + o;
        any |= __shfl_down(any, off);
    }
    __shared__ float sacc[4];
    __shared__ int   sany[4];
    if (lane == 0) { sacc[wv] = acc; sany[wv] = any; }
    __syncthreads();
    if (t == 0) {
        float r = sacc[0]; int a = sany[0];
        #pragma unroll
        for (int w = 1; w < 4; ++w) {
            r = (MODE == 0) ? fmaxf(r, sacc[w]) : (r + sacc[w]);
            a |= sany[w];
        }
        neigh[row] = a ? r : 0.f;
    }
}

// ---------- layer-1 aggregate from bitmask ----------
template<int MODE>
__global__ __launch_bounds__(256) void bit_agg(
    const unsigned long long* __restrict__ bm, const float* __restrict__ vals,
    float* __restrict__ neigh)
{
    const int wv = threadIdx.x >> 6, lane = threadIdx.x & 63;
    const int row = blockIdx.x * 4 + wv;              // grid = 2500 -> 10000 rows exactly
    const unsigned long long* __restrict__ brow = bm + (size_t)row * WPR;
    float acc = (MODE == 0) ? FNEG : 0.f;
    int any = 0;
    for (int w = lane; w < WPR; w += 64) {
        unsigned long long mk = brow[w];
        any |= (mk != 0ULL);
        if (mk) {
            const float* __restrict__ v = vals + (w << 6);
            #pragma unroll 8
            for (int b = 0; b < 64; ++b) {
                bool s = (mk >> b) & 1ULL;
                float x = v[b];
                if (MODE == 0) acc = s ? fmaxf(acc, x) : acc;
                else           acc += s ? x : 0.f;
            }
        }
    }
    #pragma unroll
    for (int off = 32; off; off >>= 1) {
        float o = __shfl_down(acc, off);
        acc = (MODE == 0) ? fmaxf(acc, o) : acc + o;
        any |= __shfl_down(any, off);
    }
    if (lane == 0) neigh[row] = any ? acc : 0.f;
}

// ---------- bf16 MFMA GEMM: C[M][256] = A[M][256] @ W^T + neigh⊗wsum ----------
// MODE 0: relu, store bf16 y + fp32 col0 ; MODE 1: identity, store fp32
template<int MODE>
__global__ __launch_bounds__(256) void gemm_mfma(
    const unsigned short* __restrict__ A0, const unsigned short* __restrict__ W0,
    const float* __restrict__ ng0, const float* __restrict__ ws0,
    void* __restrict__ out0, float* __restrict__ col0p,
    const unsigned short* __restrict__ A1, const unsigned short* __restrict__ W1,
    const float* __restrict__ ng1, const float* __restrict__ ws1,
    void* __restrict__ out1, float* __restrict__ col1p, int M)
{
    const unsigned short *A, *W; const float *ng, *wsum; void* out; float* colp;
    if (blockIdx.z == 0) { A = A0; W = W0; ng = ng0; wsum = ws0; out = out0; colp = col0p; }
    else                 { A = A1; W = W1; ng = ng1; wsum = ws1; out = out1; colp = col1p; }

    const int row0 = blockIdx.y * 64;
    const int colB = blockIdx.x * 128;
    const int t = threadIdx.x;
    const int wv = t >> 6, lane = t & 63;
    const int m = lane & 15, quad = lane >> 4;

    __shared__ __attribute__((aligned(16))) short As[64 * 40];   // [row][k], stride 40 bf16
    __shared__ __attribute__((aligned(16))) short Bs[128 * 40];  // [col][k] == W natural layout

    f32x4 acc[8];
    #pragma unroll
    for (int c = 0; c < 8; ++c) acc[c] = (f32x4){0.f, 0.f, 0.f, 0.f};

    const int ar = t >> 2, ah = t & 3;   // staging: row/col t/4, 16B segment t%4
    for (int kb = 0; kb < 8; ++kb) {
        {   // A tile: 64 rows x 32 k
            int gr = row0 + ar;
            uint4 v = make_uint4(0u, 0u, 0u, 0u);
            if (gr < M) v = *(const uint4*)(A + (size_t)gr * DD + kb * 32 + ah * 8);
            *(uint4*)(As + ar * 40 + ah * 8) = v;
        }
        #pragma unroll
        for (int i = 0; i < 2; ++i) {   // B tile: 128 cols x 32 k
            int c = i * 64 + ar;
            uint4 v = *(const uint4*)(W + (size_t)(colB + c) * DD + kb * 32 + ah * 8);
            *(uint4*)(Bs + c * 40 + ah * 8) = v;
        }
        __syncthreads();
        bf16x8 a = *(const bf16x8*)(As + (wv * 16 + m) * 40 + quad * 8);
        #pragma unroll
        for (int c = 0; c < 8; ++c) {
            bf16x8 b = *(const bf16x8*)(Bs + (c * 16 + m) * 40 + quad * 8);
            acc[c] = __builtin_amdgcn_mfma_f32_16x16x32_bf16(a, b, acc[c], 0, 0, 0);
        }
        __syncthreads();
    }

    const int orow = row0 + wv * 16 + quad * 4;
    #pragma unroll
    for (int c = 0; c < 8; ++c) {
        int gc = colB + c * 16 + m;
        float wsv = wsum[gc];
        #pragma unroll
        for (int r = 0; r < 4; ++r) {
            int gr = orow + r;
            if (gr < M) {
                float v = acc[c][r] + ng[gr] * wsv;
                if (MODE == 0) {
                    v = fmaxf(v, 0.f);
                    ((unsigned short*)out)[(size_t)gr * DD + gc] = (unsigned short)f2bf(v);
                    if (gc == 0) colp[gr] = v;   // exact fp32 col0 for layer-1 aggregation
                } else {
                    ((float*)out)[(size_t)gr * DD + gc] = v;
                }
            }
        }
    }
}

extern "C" void kernel_launch(void* const* d_in, const int* in_sizes, int n_in,
                              void* d_out, int out_size, void* d_ws, size_t ws_size,
                              hipStream_t stream) {
    const float* x1    = (const float*)d_in[0];
    const float* x2    = (const float*)d_in[1];
    const int*   adj12 = (const int*)d_in[2];
    const int*   adj21 = (const int*)d_in[3];
    const float* w1s0  = (const float*)d_in[4];
    const float* w1n0  = (const float*)d_in[5];
    const float* w2s0  = (const float*)d_in[6];
    const float* w2n0  = (const float*)d_in[7];
    const float* w1s1  = (const float*)d_in[8];
    const float* w1n1  = (const float*)d_in[9];
    const float* w2s1  = (const float*)d_in[10];
    const float* w2n1  = (const float*)d_in[11];

    char* ws = (char*)d_ws;
    size_t off = 0;
    auto alloc = [&](size_t bytes) { char* p = ws + off; off += (bytes + 15) & ~15ull; return p; };

    unsigned long long* bm21 = (unsigned long long*)alloc((size_t)NN * WPR * 8); // 12.8 MB
    unsigned long long* bm12 = (unsigned long long*)alloc((size_t)NN * WPR * 8); // 12.8 MB
    unsigned short* xb1 = (unsigned short*)alloc((size_t)NN * DD * 2);           // 5.12 MB
    unsigned short* xb2 = (unsigned short*)alloc((size_t)NN * DD * 2);
    unsigned short* yb1 = (unsigned short*)alloc((size_t)NN * DD * 2);
    unsigned short* yb2 = (unsigned short*)alloc((size_t)NN * DD * 2);
    unsigned short* wb  = (unsigned short*)alloc(4ull * DD * DD * 2);            // 0.5 MB
    float* wsum = (float*)alloc(4ull * DD * 4);
    float* x1c  = (float*)alloc(COLPAD * 4);
    float* x2c  = (float*)alloc(COLPAD * 4);
    float* y1c  = (float*)alloc(COLPAD * 4);
    float* y2c  = (float*)alloc(COLPAD * 4);
    float* n1_0 = (float*)alloc(COLPAD * 4);
    float* n2_0 = (float*)alloc(COLPAD * 4);
    float* n1_1 = (float*)alloc(COLPAD * 4);
    float* n2_1 = (float*)alloc(COLPAD * 4);
    (void)ws_size; (void)in_sizes; (void)n_in; (void)out_size;

    float* out1 = (float*)d_out;
    float* out2 = out1 + (size_t)NN * DD;

    // 1. inputs -> bf16 (+ col0 extraction)
    convert_x<<<dim3(2500, 2), 256, 0, stream>>>(x1, x2, xb1, xb2, x1c, x2c);
    // 2. self-weights -> bf16 (natural layout)
    convert_w<<<dim3(64, 4), 256, 0, stream>>>(w1s0, w2s0, w1s1, w2s1, wb);
    // 3. neighbor-weight row sums
    wn_rowsum<<<dim3(DD, 4), 64, 0, stream>>>(w1n0, w2n0, w1n1, w2n1, wsum);
    // 4. adjacency single pass: bitmask + layer-0 aggregates
    pack_agg<0><<<NN, 256, 0, stream>>>(adj21, x2c, bm21, n1_0);   // masked max -> neigh1
    pack_agg<1><<<NN, 256, 0, stream>>>(adj12, x1c, bm12, n2_0);   // masked sum -> neigh2
    // 5. layer 0 GEMMs (relu)
    gemm_mfma<0><<<dim3(2, 157, 2), 256, 0, stream>>>(
        xb1, wb + 0 * DD * DD, n1_0, wsum + 0 * DD, (void*)yb1, y1c,
        xb2, wb + 1 * DD * DD, n2_0, wsum + 1 * DD, (void*)yb2, y2c, NN);
    // 6. layer-1 aggregates from bitmasks
    bit_agg<0><<<2500, 256, 0, stream>>>(bm21, y2c, n1_1);
    bit_agg<1><<<2500, 256, 0, stream>>>(bm12, y1c, n2_1);
    // 7. layer 1 GEMMs (identity) -> outputs
    gemm_mfma<1><<<dim3(2, 157, 2), 256, 0, stream>>>(
        yb1, wb + 2 * DD * DD, n1_1, wsum + 2 * DD, (void*)out1, (float*)nullptr,
        yb2, wb + 3 * DD * DD, n2_1, wsum + 3 * DD, (void*)out2, (float*)nullptr, NN);
}

// Round 2
// 1049.986 us; speedup vs baseline: 1.0036x; 1.0036x over previous
//
#include <hip/hip_runtime.h>
#include <stdint.h>

#define NN 10000
#define DD 256
#define WPR 160            // uint64 words per bitmask row (160*64 = 10240 bits)
#define COLPAD 10240       // padded column-vector length (so aggregation loads stay in-bounds)
#define FNEG -3.402823466e38f

typedef __attribute__((ext_vector_type(8))) short bf16x8;
typedef __attribute__((ext_vector_type(4))) float f32x4;

static __device__ __forceinline__ unsigned int f2bf(float f) {
    unsigned int u = __float_as_uint(f);
    return (u + 0x7fffu + ((u >> 16) & 1u)) >> 16;   // round-to-nearest-even
}

// ---------- x: f32 -> bf16, plus extract column 0 (fp32) ----------
__global__ __launch_bounds__(256) void convert_x(
    const float* __restrict__ x1, const float* __restrict__ x2,
    unsigned short* __restrict__ xb1, unsigned short* __restrict__ xb2,
    float* __restrict__ c1, float* __restrict__ c2)
{
    const float* x; unsigned short* xb; float* cp;
    if (blockIdx.y == 0) { x = x1; xb = xb1; cp = c1; }
    else                 { x = x2; xb = xb2; cp = c2; }
    int i = (blockIdx.x * 256 + threadIdx.x) * 4;     // grid.x=2500 -> covers 2,560,000 exactly
    float4 v = *(const float4*)(x + i);
    uint2 p;
    p.x = f2bf(v.x) | (f2bf(v.y) << 16);
    p.y = f2bf(v.z) | (f2bf(v.w) << 16);
    *(uint2*)(xb + i) = p;
    if ((i & (DD - 1)) == 0) cp[i >> 8] = v.x;
}

// ---------- ws weights: f32 -> bf16 (layout preserved: W[d][k]) ----------
__global__ __launch_bounds__(256) void convert_w(
    const float* __restrict__ w0, const float* __restrict__ w1,
    const float* __restrict__ w2, const float* __restrict__ w3,
    unsigned short* __restrict__ wb)
{
    const float* w = (blockIdx.y == 0) ? w0 : (blockIdx.y == 1) ? w1
                   : (blockIdx.y == 2) ? w2 : w3;
    unsigned short* o = wb + (size_t)blockIdx.y * DD * DD;
    int i = (blockIdx.x * 256 + threadIdx.x) * 4;     // grid.x=64 -> 65536 exactly
    float4 v = *(const float4*)(w + i);
    uint2 p;
    p.x = f2bf(v.x) | (f2bf(v.y) << 16);
    p.y = f2bf(v.z) | (f2bf(v.w) << 16);
    *(uint2*)(o + i) = p;
}

// ---------- wn row sums: wsum[m][d] = sum_k wn_m[d][k] ----------
__global__ void wn_rowsum(
    const float* __restrict__ w0, const float* __restrict__ w1,
    const float* __restrict__ w2, const float* __restrict__ w3,
    float* __restrict__ wsum)
{
    const float* w = (blockIdx.y == 0) ? w0 : (blockIdx.y == 1) ? w1
                   : (blockIdx.y == 2) ? w2 : w3;
    int d = blockIdx.x, lane = threadIdx.x;           // block = 64
    float s = 0.f;
    for (int k = lane; k < DD; k += 64) s += w[d * DD + k];
    #pragma unroll
    for (int off = 32; off; off >>= 1) s += __shfl_down(s, off);
    if (lane == 0) wsum[blockIdx.y * DD + d] = s;
}

// ---------- fused: read adjacency once -> bitmask + layer-0 aggregate ----------
// Bit convention: bit j of word W (within a row) <-> column 64*W + j.
// MODE 0: masked MAX of vals ; MODE 1: masked SUM of vals
template<int MODE>
__global__ __launch_bounds__(256) void pack_agg(
    const int* __restrict__ adj, const float* __restrict__ vals,
    unsigned long long* __restrict__ bm, float* __restrict__ neigh)
{
    const int row = blockIdx.x;
    const int* __restrict__ arow = adj + (size_t)row * NN;
    unsigned long long* __restrict__ brow = bm + (size_t)row * WPR;
    const int t = threadIdx.x, wv = t >> 6, lane = t & 63;

    float acc = (MODE == 0) ? FNEG : 0.f;
    int any = 0;
    #pragma unroll
    for (int it = 0; it < 10; ++it) {
        int c = it * 1024 + wv * 256 + lane;          // 4 strided columns per thread
        int c1 = c + 64, c2 = c + 128, c3 = c + 192;
        int v0 = (c  < NN) ? arow[c]  : 0;
        int v1 = (c1 < NN) ? arow[c1] : 0;
        int v2 = (c2 < NN) ? arow[c2] : 0;
        int v3 = (c3 < NN) ? arow[c3] : 0;
        float x0 = vals[c], x1 = vals[c1], x2 = vals[c2], x3 = vals[c3]; // COLPAD buffer
        unsigned long long b0 = __ballot(v0 > 0);
        unsigned long long b1 = __ballot(v1 > 0);
        unsigned long long b2 = __ballot(v2 > 0);
        unsigned long long b3 = __ballot(v3 > 0);
        if (lane == 0) {
            int wbase = it * 16 + wv * 4;
            brow[wbase + 0] = b0; brow[wbase + 1] = b1;
            brow[wbase + 2] = b2; brow[wbase + 3] = b3;
        }
        if (MODE == 0) {
            acc = (v0 > 0) ? fmaxf(acc, x0) : acc;
            acc = (v1 > 0) ? fmaxf(acc, x1) : acc;
            acc = (v2 > 0) ? fmaxf(acc, x2) : acc;
            acc = (v3 > 0) ? fmaxf(acc, x3) : acc;
        } else {
            acc += (v0 > 0) ? x0 : 0.f;
            acc += (v1 > 0) ? x1 : 0.f;
            acc += (v2 > 0) ? x2 : 0.f;
            acc += (v3 > 0) ? x3 : 0.f;
        }
        any |= (v0 > 0) | (v1 > 0) | (v2 > 0) | (v3 > 0);
    }
    #pragma unroll
    for (int off = 32; off; off >>= 1) {
        float o = __shfl_down(acc, off);
        acc = (MODE == 0) ? fmaxf(acc, o) : acc + o;
        any |= __shfl_down(any, off);
    }
    __shared__ float sacc[4];
    __shared__ int   sany[4];
    if (lane == 0) { sacc[wv] = acc; sany[wv] = any; }
    __syncthreads();
    if (t == 0) {
        float r = sacc[0]; int a = sany[0];
        #pragma unroll
        for (int w = 1; w < 4; ++w) {
            r = (MODE == 0) ? fmaxf(r, sacc[w]) : (r + sacc[w]);
            a |= sany[w];
        }
        neigh[row] = a ? r : 0.f;
    }
}

// ---------- layer-1 aggregate from bitmask ----------
// One wave per row. All lanes load the same mask word (HW broadcast, 1 line),
// lane j owns bit j -> vals[w*64+j] is a fully coalesced 256B load.
// (Round-1 version did per-bit scalar loads with lane bases 16KB apart:
//  64 distinct lines per load instruction -> ~165us/dispatch. This is the fix.)
template<int MODE>
__global__ __launch_bounds__(256) void bit_agg(
    const unsigned long long* __restrict__ bm, const float* __restrict__ vals,
    float* __restrict__ neigh)
{
    const int wv = threadIdx.x >> 6, lane = threadIdx.x & 63;
    const int row = blockIdx.x * 4 + wv;              // grid = 2500 -> 10000 rows exactly
    const unsigned long long* __restrict__ brow = bm + (size_t)row * WPR;
    float acc = (MODE == 0) ? FNEG : 0.f;
    unsigned long long anyw = 0ULL;
    #pragma unroll 4
    for (int w = 0; w < WPR; ++w) {
        unsigned long long mk = brow[w];              // wave-uniform broadcast load
        float x = vals[(w << 6) | lane];              // coalesced
        anyw |= mk;
        bool s = (mk >> lane) & 1ULL;
        if (MODE == 0) acc = s ? fmaxf(acc, x) : acc;
        else           acc += s ? x : 0.f;
    }
    #pragma unroll
    for (int off = 32; off; off >>= 1) {
        float o = __shfl_down(acc, off);
        acc = (MODE == 0) ? fmaxf(acc, o) : acc + o;
    }
    if (lane == 0) neigh[row] = anyw ? acc : 0.f;
}

// ---------- bf16 MFMA GEMM: C[M][256] = A[M][256] @ W^T + neigh⊗wsum ----------
// MODE 0: relu, store bf16 y + fp32 col0 ; MODE 1: identity, store fp32
template<int MODE>
__global__ __launch_bounds__(256) void gemm_mfma(
    const unsigned short* __restrict__ A0, const unsigned short* __restrict__ W0,
    const float* __restrict__ ng0, const float* __restrict__ ws0,
    void* __restrict__ out0, float* __restrict__ col0p,
    const unsigned short* __restrict__ A1, const unsigned short* __restrict__ W1,
    const float* __restrict__ ng1, const float* __restrict__ ws1,
    void* __restrict__ out1, float* __restrict__ col1p, int M)
{
    const unsigned short *A, *W; const float *ng, *wsum; void* out; float* colp;
    if (blockIdx.z == 0) { A = A0; W = W0; ng = ng0; wsum = ws0; out = out0; colp = col0p; }
    else                 { A = A1; W = W1; ng = ng1; wsum = ws1; out = out1; colp = col1p; }

    const int row0 = blockIdx.y * 64;
    const int colB = blockIdx.x * 128;
    const int t = threadIdx.x;
    const int wv = t >> 6, lane = t & 63;
    const int m = lane & 15, quad = lane >> 4;

    __shared__ __attribute__((aligned(16))) short As[64 * 40];   // [row][k], stride 40 bf16
    __shared__ __attribute__((aligned(16))) short Bs[128 * 40];  // [col][k] == W natural layout

    f32x4 acc[8];
    #pragma unroll
    for (int c = 0; c < 8; ++c) acc[c] = (f32x4){0.f, 0.f, 0.f, 0.f};

    const int ar = t >> 2, ah = t & 3;   // staging: row/col t/4, 16B segment t%4
    for (int kb = 0; kb < 8; ++kb) {
        {   // A tile: 64 rows x 32 k
            int gr = row0 + ar;
            uint4 v = make_uint4(0u, 0u, 0u, 0u);
            if (gr < M) v = *(const uint4*)(A + (size_t)gr * DD + kb * 32 + ah * 8);
            *(uint4*)(As + ar * 40 + ah * 8) = v;
        }
        #pragma unroll
        for (int i = 0; i < 2; ++i) {   // B tile: 128 cols x 32 k
            int c = i * 64 + ar;
            uint4 v = *(const uint4*)(W + (size_t)(colB + c) * DD + kb * 32 + ah * 8);
            *(uint4*)(Bs + c * 40 + ah * 8) = v;
        }
        __syncthreads();
        bf16x8 a = *(const bf16x8*)(As + (wv * 16 + m) * 40 + quad * 8);
        #pragma unroll
        for (int c = 0; c < 8; ++c) {
            bf16x8 b = *(const bf16x8*)(Bs + (c * 16 + m) * 40 + quad * 8);
            acc[c] = __builtin_amdgcn_mfma_f32_16x16x32_bf16(a, b, acc[c], 0, 0, 0);
        }
        __syncthreads();
    }

    const int orow = row0 + wv * 16 + quad * 4;
    #pragma unroll
    for (int c = 0; c < 8; ++c) {
        int gc = colB + c * 16 + m;
        float wsv = wsum[gc];
        #pragma unroll
        for (int r = 0; r < 4; ++r) {
            int gr = orow + r;
            if (gr < M) {
                float v = acc[c][r] + ng[gr] * wsv;
                if (MODE == 0) {
                    v = fmaxf(v, 0.f);
                    ((unsigned short*)out)[(size_t)gr * DD + gc] = (unsigned short)f2bf(v);
                    if (gc == 0) colp[gr] = v;   // exact fp32 col0 for layer-1 aggregation
                } else {
                    ((float*)out)[(size_t)gr * DD + gc] = v;
                }
            }
        }
    }
}

extern "C" void kernel_launch(void* const* d_in, const int* in_sizes, int n_in,
                              void* d_out, int out_size, void* d_ws, size_t ws_size,
                              hipStream_t stream) {
    const float* x1    = (const float*)d_in[0];
    const float* x2    = (const float*)d_in[1];
    const int*   adj12 = (const int*)d_in[2];
    const int*   adj21 = (const int*)d_in[3];
    const float* w1s0  = (const float*)d_in[4];
    const float* w1n0  = (const float*)d_in[5];
    const float* w2s0  = (const float*)d_in[6];
    const float* w2n0  = (const float*)d_in[7];
    const float* w1s1  = (const float*)d_in[8];
    const float* w1n1  = (const float*)d_in[9];
    const float* w2s1  = (const float*)d_in[10];
    const float* w2n1  = (const float*)d_in[11];

    char* ws = (char*)d_ws;
    size_t off = 0;
    auto alloc = [&](size_t bytes) { char* p = ws + off; off += (bytes + 15) & ~15ull; return p; };

    unsigned long long* bm21 = (unsigned long long*)alloc((size_t)NN * WPR * 8); // 12.8 MB
    unsigned long long* bm12 = (unsigned long long*)alloc((size_t)NN * WPR * 8); // 12.8 MB
    unsigned short* xb1 = (unsigned short*)alloc((size_t)NN * DD * 2);           // 5.12 MB
    unsigned short* xb2 = (unsigned short*)alloc((size_t)NN * DD * 2);
    unsigned short* yb1 = (unsigned short*)alloc((size_t)NN * DD * 2);
    unsigned short* yb2 = (unsigned short*)alloc((size_t)NN * DD * 2);
    unsigned short* wb  = (unsigned short*)alloc(4ull * DD * DD * 2);            // 0.5 MB
    float* wsum = (float*)alloc(4ull * DD * 4);
    float* x1c  = (float*)alloc(COLPAD * 4);
    float* x2c  = (float*)alloc(COLPAD * 4);
    float* y1c  = (float*)alloc(COLPAD * 4);
    float* y2c  = (float*)alloc(COLPAD * 4);
    float* n1_0 = (float*)alloc(COLPAD * 4);
    float* n2_0 = (float*)alloc(COLPAD * 4);
    float* n1_1 = (float*)alloc(COLPAD * 4);
    float* n2_1 = (float*)alloc(COLPAD * 4);
    (void)ws_size; (void)in_sizes; (void)n_in; (void)out_size;

    float* out1 = (float*)d_out;
    float* out2 = out1 + (size_t)NN * DD;

    // 1. inputs -> bf16 (+ col0 extraction)
    convert_x<<<dim3(2500, 2), 256, 0, stream>>>(x1, x2, xb1, xb2, x1c, x2c);
    // 2. self-weights -> bf16 (natural layout)
    convert_w<<<dim3(64, 4), 256, 0, stream>>>(w1s0, w2s0, w1s1, w2s1, wb);
    // 3. neighbor-weight row sums
    wn_rowsum<<<dim3(DD, 4), 64, 0, stream>>>(w1n0, w2n0, w1n1, w2n1, wsum);
    // 4. adjacency single pass: bitmask + layer-0 aggregates
    pack_agg<0><<<NN, 256, 0, stream>>>(adj21, x2c, bm21, n1_0);   // masked max -> neigh1
    pack_agg<1><<<NN, 256, 0, stream>>>(adj12, x1c, bm12, n2_0);   // masked sum -> neigh2
    // 5. layer 0 GEMMs (relu)
    gemm_mfma<0><<<dim3(2, 157, 2), 256, 0, stream>>>(
        xb1, wb + 0 * DD * DD, n1_0, wsum + 0 * DD, (void*)yb1, y1c,
        xb2, wb + 1 * DD * DD, n2_0, wsum + 1 * DD, (void*)yb2, y2c, NN);
    // 6. layer-1 aggregates from bitmasks
    bit_agg<0><<<2500, 256, 0, stream>>>(bm21, y2c, n1_1);
    bit_agg<1><<<2500, 256, 0, stream>>>(bm12, y1c, n2_1);
    // 7. layer 1 GEMMs (identity) -> outputs
    gemm_mfma<1><<<dim3(2, 157, 2), 256, 0, stream>>>(
        yb1, wb + 2 * DD * DD, n1_1, wsum + 2 * DD, (void*)out1, (float*)nullptr,
        yb2, wb + 3 * DD * DD, n2_1, wsum + 3 * DD, (void*)out2, (float*)nullptr, NN);
}

// Round 3
// 914.293 us; speedup vs baseline: 1.1526x; 1.1484x over previous
//
#include <hip/hip_runtime.h>
#include <stdint.h>

#define NN 10000
#define DD 256
#define WPR 160            // uint64 words per bitmask row (40 chunks x 4 words)
#define COLPAD 10240       // padded column-vector length (2560 float4)
#define FNEG -3.402823466e38f

typedef __attribute__((ext_vector_type(8))) short bf16x8;
typedef __attribute__((ext_vector_type(4))) float f32x4;
typedef unsigned long long u64;

static __device__ __forceinline__ unsigned int f2bf(float f) {
    unsigned int u = __float_as_uint(f);
    return (u + 0x7fffu + ((u >> 16) & 1u)) >> 16;   // round-to-nearest-even
}

// ---------- x: f32 -> bf16, plus extract column 0 (fp32) ----------
__global__ __launch_bounds__(256) void convert_x(
    const float* __restrict__ x1, const float* __restrict__ x2,
    unsigned short* __restrict__ xb1, unsigned short* __restrict__ xb2,
    float* __restrict__ c1, float* __restrict__ c2)
{
    const float* x; unsigned short* xb; float* cp;
    if (blockIdx.y == 0) { x = x1; xb = xb1; cp = c1; }
    else                 { x = x2; xb = xb2; cp = c2; }
    int i = (blockIdx.x * 256 + threadIdx.x) * 4;     // grid.x=2500 -> 2,560,000 exactly
    float4 v = *(const float4*)(x + i);
    uint2 p;
    p.x = f2bf(v.x) | (f2bf(v.y) << 16);
    p.y = f2bf(v.z) | (f2bf(v.w) << 16);
    *(uint2*)(xb + i) = p;
    if ((i & (DD - 1)) == 0) cp[i >> 8] = v.x;
}

// ---------- ws weights: f32 -> bf16 (layout preserved: W[d][k]) ----------
__global__ __launch_bounds__(256) void convert_w(
    const float* __restrict__ w0, const float* __restrict__ w1,
    const float* __restrict__ w2, const float* __restrict__ w3,
    unsigned short* __restrict__ wb)
{
    const float* w = (blockIdx.y == 0) ? w0 : (blockIdx.y == 1) ? w1
                   : (blockIdx.y == 2) ? w2 : w3;
    unsigned short* o = wb + (size_t)blockIdx.y * DD * DD;
    int i = (blockIdx.x * 256 + threadIdx.x) * 4;     // grid.x=64 -> 65536 exactly
    float4 v = *(const float4*)(w + i);
    uint2 p;
    p.x = f2bf(v.x) | (f2bf(v.y) << 16);
    p.y = f2bf(v.z) | (f2bf(v.w) << 16);
    *(uint2*)(o + i) = p;
}

// ---------- wn row sums: wsum[m][d] = sum_k wn_m[d][k] ----------
__global__ void wn_rowsum(
    const float* __restrict__ w0, const float* __restrict__ w1,
    const float* __restrict__ w2, const float* __restrict__ w3,
    float* __restrict__ wsum)
{
    const float* w = (blockIdx.y == 0) ? w0 : (blockIdx.y == 1) ? w1
                   : (blockIdx.y == 2) ? w2 : w3;
    int d = blockIdx.x, lane = threadIdx.x;           // block = 64
    float s = 0.f;
    for (int k = lane; k < DD; k += 64) s += w[d * DD + k];
    #pragma unroll
    for (int off = 32; off; off >>= 1) s += __shfl_down(s, off);
    if (lane == 0) wsum[blockIdx.y * DD + d] = s;
}

// ---------- fused pack + layer-0 aggregate, BOTH matrices in one dispatch ----
// Bit convention: chunk ch covers cols [256ch, 256ch+255]; word (4ch+i), bit j
// <-> column 256ch + 4j + i  (lane j holds int4 of 4 consecutive columns).
// blocks [0,NN): adj21, masked MAX of x2c -> bm21, n1.
// blocks [NN,2NN): adj12, masked SUM of x1c -> bm12, n2.
__global__ __launch_bounds__(256) void pack_agg2(
    const int* __restrict__ adj21, const int* __restrict__ adj12,
    const float* __restrict__ x2c, const float* __restrict__ x1c,
    u64* __restrict__ bm21, u64* __restrict__ bm12,
    float* __restrict__ n1, float* __restrict__ n2)
{
    const int b = blockIdx.x;
    const bool isMax = (b < NN);
    const int row = isMax ? b : b - NN;
    const int4* __restrict__ arow4 =
        (const int4*)((isMax ? adj21 : adj12) + (size_t)row * NN);
    const float4* __restrict__ vals4 = (const float4*)(isMax ? x2c : x1c);
    u64* __restrict__ brow = (isMax ? bm21 : bm12) + (size_t)row * WPR;

    const int t = threadIdx.x, wv = t >> 6, lane = t & 63;
    float accM = FNEG, accS = 0.f;
    u64 anyw = 0ULL;

    #pragma unroll
    for (int i = 0; i < 10; ++i) {
        const int ch  = wv + i * 4;        // wave wv owns chunks wv, wv+4, ...
        const int idx = ch * 64 + lane;    // int4 index into the row
        int4 v = make_int4(0, 0, 0, 0);
        if (idx < NN / 4) v = arow4[idx];  // only chunk 39 lanes >=4 are OOB
        float4 xv = vals4[idx];            // COLPAD buffer: always in-bounds
        u64 b0 = __ballot(v.x > 0);
        u64 b1 = __ballot(v.y > 0);
        u64 b2 = __ballot(v.z > 0);
        u64 b3 = __ballot(v.w > 0);
        if (lane < 4) {
            u64 w = (lane == 0) ? b0 : (lane == 1) ? b1 : (lane == 2) ? b2 : b3;
            brow[ch * 4 + lane] = w;       // coalesced 32B store
        }
        anyw |= (b0 | b1 | b2 | b3);
        // per-lane aggregation from own decisions (no bit extraction needed)
        accM = (v.x > 0) ? fmaxf(accM, xv.x) : accM;
        accM = (v.y > 0) ? fmaxf(accM, xv.y) : accM;
        accM = (v.z > 0) ? fmaxf(accM, xv.z) : accM;
        accM = (v.w > 0) ? fmaxf(accM, xv.w) : accM;
        accS += (v.x > 0) ? xv.x : 0.f;
        accS += (v.y > 0) ? xv.y : 0.f;
        accS += (v.z > 0) ? xv.z : 0.f;
        accS += (v.w > 0) ? xv.w : 0.f;
    }
    #pragma unroll
    for (int off = 32; off; off >>= 1) {
        accM = fmaxf(accM, __shfl_down(accM, off));
        accS += __shfl_down(accS, off);
    }
    __shared__ float sM[4], sS[4];
    __shared__ u64   sA[4];
    if (lane == 0) { sM[wv] = accM; sS[wv] = accS; sA[wv] = anyw; }
    __syncthreads();
    if (t == 0) {
        float rM = sM[0], rS = sS[0]; u64 a = sA[0];
        #pragma unroll
        for (int w = 1; w < 4; ++w) { rM = fmaxf(rM, sM[w]); rS += sS[w]; a |= sA[w]; }
        float r = isMax ? rM : rS;
        (isMax ? n1 : n2)[row] = a ? r : 0.f;
    }
}

// ---------- layer-1 aggregate from bitmask, BOTH matrices in one dispatch ----
// One wave per row; 40 chunks; 4 broadcast mask words + one coalesced float4
// per chunk (16B/lane). blocks [0,2500): bm21/max/y2c -> n1; else bm12/sum/y1c.
__global__ __launch_bounds__(256) void bit_agg2(
    const u64* __restrict__ bm21, const u64* __restrict__ bm12,
    const float* __restrict__ y2c, const float* __restrict__ y1c,
    float* __restrict__ n1, float* __restrict__ n2)
{
    const int b = blockIdx.x;
    const bool isMax = (b < 2500);
    const int wv = threadIdx.x >> 6, lane = threadIdx.x & 63;
    const int row = (isMax ? b : b - 2500) * 4 + wv;  // covers 0..9999 each half
    const u64* __restrict__ brow = (isMax ? bm21 : bm12) + (size_t)row * WPR;
    const float4* __restrict__ vals4 = (const float4*)(isMax ? y2c : y1c);

    float accM = FNEG, accS = 0.f;
    u64 anyw = 0ULL;
    #pragma unroll 4
    for (int ch = 0; ch < 40; ++ch) {
        u64 m0 = brow[ch * 4 + 0];         // wave-uniform broadcast loads
        u64 m1 = brow[ch * 4 + 1];
        u64 m2 = brow[ch * 4 + 2];
        u64 m3 = brow[ch * 4 + 3];
        float4 xv = vals4[ch * 64 + lane]; // coalesced 1KB/wave
        anyw |= (m0 | m1 | m2 | m3);
        bool s0 = (m0 >> lane) & 1ULL;
        bool s1 = (m1 >> lane) & 1ULL;
        bool s2 = (m2 >> lane) & 1ULL;
        bool s3 = (m3 >> lane) & 1ULL;
        accM = s0 ? fmaxf(accM, xv.x) : accM;
        accM = s1 ? fmaxf(accM, xv.y) : accM;
        accM = s2 ? fmaxf(accM, xv.z) : accM;
        accM = s3 ? fmaxf(accM, xv.w) : accM;
        accS += s0 ? xv.x : 0.f;
        accS += s1 ? xv.y : 0.f;
        accS += s2 ? xv.z : 0.f;
        accS += s3 ? xv.w : 0.f;
    }
    #pragma unroll
    for (int off = 32; off; off >>= 1) {
        accM = fmaxf(accM, __shfl_down(accM, off));
        accS += __shfl_down(accS, off);
    }
    if (lane == 0) {
        float r = isMax ? accM : accS;
        (isMax ? n1 : n2)[row] = anyw ? r : 0.f;
    }
}

// ---------- bf16 MFMA GEMM: C[M][256] = A[M][256] @ W^T + neigh⊗wsum ----------
// MODE 0: relu, store bf16 y + fp32 col0 ; MODE 1: identity, store fp32
template<int MODE>
__global__ __launch_bounds__(256) void gemm_mfma(
    const unsigned short* __restrict__ A0, const unsigned short* __restrict__ W0,
    const float* __restrict__ ng0, const float* __restrict__ ws0,
    void* __restrict__ out0, float* __restrict__ col0p,
    const unsigned short* __restrict__ A1, const unsigned short* __restrict__ W1,
    const float* __restrict__ ng1, const float* __restrict__ ws1,
    void* __restrict__ out1, float* __restrict__ col1p, int M)
{
    const unsigned short *A, *W; const float *ng, *wsum; void* out; float* colp;
    if (blockIdx.z == 0) { A = A0; W = W0; ng = ng0; wsum = ws0; out = out0; colp = col0p; }
    else                 { A = A1; W = W1; ng = ng1; wsum = ws1; out = out1; colp = col1p; }

    const int row0 = blockIdx.y * 64;
    const int colB = blockIdx.x * 128;
    const int t = threadIdx.x;
    const int wv = t >> 6, lane = t & 63;
    const int m = lane & 15, quad = lane >> 4;

    __shared__ __attribute__((aligned(16))) short As[64 * 40];   // [row][k], stride 40
    __shared__ __attribute__((aligned(16))) short Bs[128 * 40];  // [col][k]

    f32x4 acc[8];
    #pragma unroll
    for (int c = 0; c < 8; ++c) acc[c] = (f32x4){0.f, 0.f, 0.f, 0.f};

    const int ar = t >> 2, ah = t & 3;
    for (int kb = 0; kb < 8; ++kb) {
        {   // A tile: 64 rows x 32 k
            int gr = row0 + ar;
            uint4 v = make_uint4(0u, 0u, 0u, 0u);
            if (gr < M) v = *(const uint4*)(A + (size_t)gr * DD + kb * 32 + ah * 8);
            *(uint4*)(As + ar * 40 + ah * 8) = v;
        }
        #pragma unroll
        for (int i = 0; i < 2; ++i) {   // B tile: 128 cols x 32 k
            int c = i * 64 + ar;
            uint4 v = *(const uint4*)(W + (size_t)(colB + c) * DD + kb * 32 + ah * 8);
            *(uint4*)(Bs + c * 40 + ah * 8) = v;
        }
        __syncthreads();
        bf16x8 a = *(const bf16x8*)(As + (wv * 16 + m) * 40 + quad * 8);
        #pragma unroll
        for (int c = 0; c < 8; ++c) {
            bf16x8 bfr = *(const bf16x8*)(Bs + (c * 16 + m) * 40 + quad * 8);
            acc[c] = __builtin_amdgcn_mfma_f32_16x16x32_bf16(a, bfr, acc[c], 0, 0, 0);
        }
        __syncthreads();
    }

    const int orow = row0 + wv * 16 + quad * 4;
    #pragma unroll
    for (int c = 0; c < 8; ++c) {
        int gc = colB + c * 16 + m;
        float wsv = wsum[gc];
        #pragma unroll
        for (int r = 0; r < 4; ++r) {
            int gr = orow + r;
            if (gr < M) {
                float v = acc[c][r] + ng[gr] * wsv;
                if (MODE == 0) {
                    v = fmaxf(v, 0.f);
                    ((unsigned short*)out)[(size_t)gr * DD + gc] = (unsigned short)f2bf(v);
                    if (gc == 0) colp[gr] = v;   // exact fp32 col0 for layer-1 agg
                } else {
                    ((float*)out)[(size_t)gr * DD + gc] = v;
                }
            }
        }
    }
}

extern "C" void kernel_launch(void* const* d_in, const int* in_sizes, int n_in,
                              void* d_out, int out_size, void* d_ws, size_t ws_size,
                              hipStream_t stream) {
    const float* x1    = (const float*)d_in[0];
    const float* x2    = (const float*)d_in[1];
    const int*   adj12 = (const int*)d_in[2];
    const int*   adj21 = (const int*)d_in[3];
    const float* w1s0  = (const float*)d_in[4];
    const float* w1n0  = (const float*)d_in[5];
    const float* w2s0  = (const float*)d_in[6];
    const float* w2n0  = (const float*)d_in[7];
    const float* w1s1  = (const float*)d_in[8];
    const float* w1n1  = (const float*)d_in[9];
    const float* w2s1  = (const float*)d_in[10];
    const float* w2n1  = (const float*)d_in[11];

    char* ws = (char*)d_ws;
    size_t off = 0;
    auto alloc = [&](size_t bytes) { char* p = ws + off; off += (bytes + 15) & ~15ull; return p; };

    u64* bm21 = (u64*)alloc((size_t)NN * WPR * 8);                     // 12.8 MB
    u64* bm12 = (u64*)alloc((size_t)NN * WPR * 8);                     // 12.8 MB
    unsigned short* xb1 = (unsigned short*)alloc((size_t)NN * DD * 2); // 5.12 MB
    unsigned short* xb2 = (unsigned short*)alloc((size_t)NN * DD * 2);
    unsigned short* yb1 = (unsigned short*)alloc((size_t)NN * DD * 2);
    unsigned short* yb2 = (unsigned short*)alloc((size_t)NN * DD * 2);
    unsigned short* wb  = (unsigned short*)alloc(4ull * DD * DD * 2);  // 0.5 MB
    float* wsum = (float*)alloc(4ull * DD * 4);
    float* x1c  = (float*)alloc(COLPAD * 4);
    float* x2c  = (float*)alloc(COLPAD * 4);
    float* y1c  = (float*)alloc(COLPAD * 4);
    float* y2c  = (float*)alloc(COLPAD * 4);
    float* n1_0 = (float*)alloc(COLPAD * 4);
    float* n2_0 = (float*)alloc(COLPAD * 4);
    float* n1_1 = (float*)alloc(COLPAD * 4);
    float* n2_1 = (float*)alloc(COLPAD * 4);
    (void)ws_size; (void)in_sizes; (void)n_in; (void)out_size;

    float* out1 = (float*)d_out;
    float* out2 = out1 + (size_t)NN * DD;

    // 1. inputs -> bf16 (+ col0 extraction)
    convert_x<<<dim3(2500, 2), 256, 0, stream>>>(x1, x2, xb1, xb2, x1c, x2c);
    // 2. self-weights -> bf16
    convert_w<<<dim3(64, 4), 256, 0, stream>>>(w1s0, w2s0, w1s1, w2s1, wb);
    // 3. neighbor-weight row sums
    wn_rowsum<<<dim3(DD, 4), 64, 0, stream>>>(w1n0, w2n0, w1n1, w2n1, wsum);
    // 4. single adjacency pass (both matrices): bitmasks + layer-0 aggregates
    pack_agg2<<<2 * NN, 256, 0, stream>>>(adj21, adj12, x2c, x1c, bm21, bm12, n1_0, n2_0);
    // 5. layer 0 GEMMs (relu)
    gemm_mfma<0><<<dim3(2, 157, 2), 256, 0, stream>>>(
        xb1, wb + 0 * DD * DD, n1_0, wsum + 0 * DD, (void*)yb1, y1c,
        xb2, wb + 1 * DD * DD, n2_0, wsum + 1 * DD, (void*)yb2, y2c, NN);
    // 6. layer-1 aggregates from bitmasks (both matrices)
    bit_agg2<<<5000, 256, 0, stream>>>(bm21, bm12, y2c, y1c, n1_1, n2_1);
    // 7. layer 1 GEMMs (identity) -> outputs
    gemm_mfma<1><<<dim3(2, 157, 2), 256, 0, stream>>>(
        yb1, wb + 2 * DD * DD, n1_1, wsum + 2 * DD, (void*)out1, (float*)nullptr,
        yb2, wb + 3 * DD * DD, n2_1, wsum + 3 * DD, (void*)out2, (float*)nullptr, NN);
}

// Round 4
// 901.189 us; speedup vs baseline: 1.1693x; 1.0145x over previous
//
#include <hip/hip_runtime.h>
#include <stdint.h>

#define NN 10000
#define DD 256
#define WPR 160            // uint64 words per bitmask row (40 chunks x 4 words)
#define COLPAD 10240       // padded column-vector length (2560 float4)
#define FNEG -3.402823466e38f

typedef __attribute__((ext_vector_type(8))) short bf16x8;
typedef __attribute__((ext_vector_type(4))) float f32x4;
typedef unsigned long long u64;

static __device__ __forceinline__ unsigned int f2bf(float f) {
    unsigned int u = __float_as_uint(f);
    return (u + 0x7fffu + ((u >> 16) & 1u)) >> 16;   // round-to-nearest-even
}

// ---------- fused prep: x->bf16 (+col0), ws->bf16, wn row-sums --------------
// blocks [0,5000): convert x1/x2 ; [5000,5256): convert ws ; [5256,5512): wn sums
__global__ __launch_bounds__(256) void prep(
    const float* __restrict__ x1, const float* __restrict__ x2,
    unsigned short* __restrict__ xb1, unsigned short* __restrict__ xb2,
    float* __restrict__ c1, float* __restrict__ c2,
    const float* __restrict__ ws0, const float* __restrict__ ws1,
    const float* __restrict__ ws2, const float* __restrict__ ws3,
    unsigned short* __restrict__ wb,
    const float* __restrict__ wn0, const float* __restrict__ wn1,
    const float* __restrict__ wn2, const float* __restrict__ wn3,
    float* __restrict__ wsum)
{
    const int b = blockIdx.x;
    if (b < 5000) {
        const float* x; unsigned short* xb; float* cp; int bx = b;
        if (bx < 2500) { x = x1; xb = xb1; cp = c1; }
        else           { x = x2; xb = xb2; cp = c2; bx -= 2500; }
        int i = (bx * 256 + threadIdx.x) * 4;         // covers 2,560,000 exactly
        float4 v = *(const float4*)(x + i);
        uint2 p;
        p.x = f2bf(v.x) | (f2bf(v.y) << 16);
        p.y = f2bf(v.z) | (f2bf(v.w) << 16);
        *(uint2*)(xb + i) = p;
        if ((i & (DD - 1)) == 0) cp[i >> 8] = v.x;
    } else if (b < 5256) {
        int idx = b - 5000, m = idx >> 6, bx = idx & 63;
        const float* w = (m == 0) ? ws0 : (m == 1) ? ws1 : (m == 2) ? ws2 : ws3;
        unsigned short* o = wb + (size_t)m * DD * DD;
        int i = (bx * 256 + threadIdx.x) * 4;         // covers 65,536 exactly
        float4 v = *(const float4*)(w + i);
        uint2 p;
        p.x = f2bf(v.x) | (f2bf(v.y) << 16);
        p.y = f2bf(v.z) | (f2bf(v.w) << 16);
        *(uint2*)(o + i) = p;
    } else {
        int idx = b - 5256, m = idx >> 6;
        const float* w = (m == 0) ? wn0 : (m == 1) ? wn1 : (m == 2) ? wn2 : wn3;
        const int wv = threadIdx.x >> 6, lane = threadIdx.x & 63;
        const int d = (idx & 63) * 4 + wv;            // 64 blocks x 4 waves = 256 d's
        float4 v = ((const float4*)w)[d * 64 + lane]; // row d, 256 floats
        float s = v.x + v.y + v.z + v.w;
        #pragma unroll
        for (int off = 32; off; off >>= 1) s += __shfl_down(s, off);
        if (lane == 0) wsum[m * DD + d] = s;
    }
}

// ---------- fused pack + layer-0 aggregate, BOTH matrices in one dispatch ----
// Bit convention: chunk ch covers cols [256ch, 256ch+255]; word (4ch+i), bit j
// <-> column 256ch + 4j + i  (lane j holds int4 of 4 consecutive columns).
// blocks [0,NN): adj21, masked MAX of x2c -> bm21, n1.
// blocks [NN,2NN): adj12, masked SUM of x1c -> bm12, n2.
__global__ __launch_bounds__(256) void pack_agg2(
    const int* __restrict__ adj21, const int* __restrict__ adj12,
    const float* __restrict__ x2c, const float* __restrict__ x1c,
    u64* __restrict__ bm21, u64* __restrict__ bm12,
    float* __restrict__ n1, float* __restrict__ n2)
{
    const int b = blockIdx.x;
    const bool isMax = (b < NN);
    const int row = isMax ? b : b - NN;
    const int4* __restrict__ arow4 =
        (const int4*)((isMax ? adj21 : adj12) + (size_t)row * NN);
    const float4* __restrict__ vals4 = (const float4*)(isMax ? x2c : x1c);
    u64* __restrict__ brow = (isMax ? bm21 : bm12) + (size_t)row * WPR;

    const int t = threadIdx.x, wv = t >> 6, lane = t & 63;
    float accM = FNEG, accS = 0.f;
    u64 anyw = 0ULL;

    #pragma unroll
    for (int i = 0; i < 10; ++i) {
        const int ch  = wv + i * 4;        // wave wv owns chunks wv, wv+4, ...
        const int idx = ch * 64 + lane;    // int4 index into the row
        int4 v = make_int4(0, 0, 0, 0);
        if (idx < NN / 4) v = arow4[idx];  // only chunk 39 lanes >=4 are OOB
        float4 xv = vals4[idx];            // COLPAD buffer: always in-bounds
        u64 b0 = __ballot(v.x > 0);
        u64 b1 = __ballot(v.y > 0);
        u64 b2 = __ballot(v.z > 0);
        u64 b3 = __ballot(v.w > 0);
        if (lane < 4) {
            u64 w = (lane == 0) ? b0 : (lane == 1) ? b1 : (lane == 2) ? b2 : b3;
            brow[ch * 4 + lane] = w;       // coalesced 32B store
        }
        anyw |= (b0 | b1 | b2 | b3);
        accM = (v.x > 0) ? fmaxf(accM, xv.x) : accM;
        accM = (v.y > 0) ? fmaxf(accM, xv.y) : accM;
        accM = (v.z > 0) ? fmaxf(accM, xv.z) : accM;
        accM = (v.w > 0) ? fmaxf(accM, xv.w) : accM;
        accS += (v.x > 0) ? xv.x : 0.f;
        accS += (v.y > 0) ? xv.y : 0.f;
        accS += (v.z > 0) ? xv.z : 0.f;
        accS += (v.w > 0) ? xv.w : 0.f;
    }
    #pragma unroll
    for (int off = 32; off; off >>= 1) {
        accM = fmaxf(accM, __shfl_down(accM, off));
        accS += __shfl_down(accS, off);
    }
    __shared__ float sM[4], sS[4];
    __shared__ u64   sA[4];
    if (lane == 0) { sM[wv] = accM; sS[wv] = accS; sA[wv] = anyw; }
    __syncthreads();
    if (t == 0) {
        float rM = sM[0], rS = sS[0]; u64 a = sA[0];
        #pragma unroll
        for (int w = 1; w < 4; ++w) { rM = fmaxf(rM, sM[w]); rS += sS[w]; a |= sA[w]; }
        float r = isMax ? rM : rS;
        (isMax ? n1 : n2)[row] = a ? r : 0.f;
    }
}

// ---------- layer-1 aggregate from bitmask: 4 rows per wave -----------------
// Each wave aggregates 4 rows against ONE vals load per chunk (4x less L1
// traffic than 1-row-per-wave). 16 rows/block; blocks [0,625): bm21/max/y2c,
// [625,1250): bm12/sum/y1c. anyw from broadcast loads is lane-uniform.
__global__ __launch_bounds__(256) void bit_agg4(
    const u64* __restrict__ bm21, const u64* __restrict__ bm12,
    const float* __restrict__ y2c, const float* __restrict__ y1c,
    float* __restrict__ n1, float* __restrict__ n2)
{
    const int b = blockIdx.x;
    const bool isMax = (b < 625);
    const int wv = threadIdx.x >> 6, lane = threadIdx.x & 63;
    const int row0 = (isMax ? b : b - 625) * 16 + wv * 4;   // wave's 4 rows
    const u64* __restrict__ bmb = isMax ? bm21 : bm12;
    const float4* __restrict__ vals4 = (const float4*)(isMax ? y2c : y1c);
    const u64* __restrict__ br0 = bmb + (size_t)(row0 + 0) * WPR;
    const u64* __restrict__ br1 = bmb + (size_t)(row0 + 1) * WPR;
    const u64* __restrict__ br2 = bmb + (size_t)(row0 + 2) * WPR;
    const u64* __restrict__ br3 = bmb + (size_t)(row0 + 3) * WPR;

    float aM[4] = {FNEG, FNEG, FNEG, FNEG};
    float aS[4] = {0.f, 0.f, 0.f, 0.f};
    u64 anyw[4] = {0ULL, 0ULL, 0ULL, 0ULL};

    #pragma unroll 2
    for (int ch = 0; ch < 40; ++ch) {
        float4 xv = vals4[ch * 64 + lane];          // coalesced, shared by 4 rows
        #pragma unroll
        for (int r = 0; r < 4; ++r) {
            const u64* br = (r == 0) ? br0 : (r == 1) ? br1 : (r == 2) ? br2 : br3;
            u64 m0 = br[ch * 4 + 0];                // wave-uniform broadcasts
            u64 m1 = br[ch * 4 + 1];
            u64 m2 = br[ch * 4 + 2];
            u64 m3 = br[ch * 4 + 3];
            anyw[r] |= (m0 | m1 | m2 | m3);
            bool s0 = (m0 >> lane) & 1ULL;
            bool s1 = (m1 >> lane) & 1ULL;
            bool s2 = (m2 >> lane) & 1ULL;
            bool s3 = (m3 >> lane) & 1ULL;
            aM[r] = s0 ? fmaxf(aM[r], xv.x) : aM[r];
            aM[r] = s1 ? fmaxf(aM[r], xv.y) : aM[r];
            aM[r] = s2 ? fmaxf(aM[r], xv.z) : aM[r];
            aM[r] = s3 ? fmaxf(aM[r], xv.w) : aM[r];
            aS[r] += s0 ? xv.x : 0.f;
            aS[r] += s1 ? xv.y : 0.f;
            aS[r] += s2 ? xv.z : 0.f;
            aS[r] += s3 ? xv.w : 0.f;
        }
    }
    #pragma unroll
    for (int r = 0; r < 4; ++r) {
        float m = aM[r], s = aS[r];
        #pragma unroll
        for (int off = 32; off; off >>= 1) {
            m = fmaxf(m, __shfl_down(m, off));
            s += __shfl_down(s, off);
        }
        if (lane == 0) {
            float res = isMax ? m : s;
            (isMax ? n1 : n2)[row0 + r] = anyw[r] ? res : 0.f;
        }
    }
}

// ---------- bf16 MFMA GEMM: C[M][256] = A[M][256] @ W^T + neigh⊗wsum ----------
// MODE 0: relu, store bf16 y + fp32 col0 ; MODE 1: identity, store fp32
template<int MODE>
__global__ __launch_bounds__(256) void gemm_mfma(
    const unsigned short* __restrict__ A0, const unsigned short* __restrict__ W0,
    const float* __restrict__ ng0, const float* __restrict__ ws0,
    void* __restrict__ out0, float* __restrict__ col0p,
    const unsigned short* __restrict__ A1, const unsigned short* __restrict__ W1,
    const float* __restrict__ ng1, const float* __restrict__ ws1,
    void* __restrict__ out1, float* __restrict__ col1p, int M)
{
    const unsigned short *A, *W; const float *ng, *wsum; void* out; float* colp;
    if (blockIdx.z == 0) { A = A0; W = W0; ng = ng0; wsum = ws0; out = out0; colp = col0p; }
    else                 { A = A1; W = W1; ng = ng1; wsum = ws1; out = out1; colp = col1p; }

    const int row0 = blockIdx.y * 64;
    const int colB = blockIdx.x * 128;
    const int t = threadIdx.x;
    const int wv = t >> 6, lane = t & 63;
    const int m = lane & 15, quad = lane >> 4;

    __shared__ __attribute__((aligned(16))) short As[64 * 40];   // [row][k], stride 40
    __shared__ __attribute__((aligned(16))) short Bs[128 * 40];  // [col][k]

    f32x4 acc[8];
    #pragma unroll
    for (int c = 0; c < 8; ++c) acc[c] = (f32x4){0.f, 0.f, 0.f, 0.f};

    const int ar = t >> 2, ah = t & 3;
    for (int kb = 0; kb < 8; ++kb) {
        {   // A tile: 64 rows x 32 k
            int gr = row0 + ar;
            uint4 v = make_uint4(0u, 0u, 0u, 0u);
            if (gr < M) v = *(const uint4*)(A + (size_t)gr * DD + kb * 32 + ah * 8);
            *(uint4*)(As + ar * 40 + ah * 8) = v;
        }
        #pragma unroll
        for (int i = 0; i < 2; ++i) {   // B tile: 128 cols x 32 k
            int c = i * 64 + ar;
            uint4 v = *(const uint4*)(W + (size_t)(colB + c) * DD + kb * 32 + ah * 8);
            *(uint4*)(Bs + c * 40 + ah * 8) = v;
        }
        __syncthreads();
        bf16x8 a = *(const bf16x8*)(As + (wv * 16 + m) * 40 + quad * 8);
        #pragma unroll
        for (int c = 0; c < 8; ++c) {
            bf16x8 bfr = *(const bf16x8*)(Bs + (c * 16 + m) * 40 + quad * 8);
            acc[c] = __builtin_amdgcn_mfma_f32_16x16x32_bf16(a, bfr, acc[c], 0, 0, 0);
        }
        __syncthreads();
    }

    const int orow = row0 + wv * 16 + quad * 4;
    #pragma unroll
    for (int c = 0; c < 8; ++c) {
        int gc = colB + c * 16 + m;
        float wsv = wsum[gc];
        #pragma unroll
        for (int r = 0; r < 4; ++r) {
            int gr = orow + r;
            if (gr < M) {
                float v = acc[c][r] + ng[gr] * wsv;
                if (MODE == 0) {
                    v = fmaxf(v, 0.f);
                    ((unsigned short*)out)[(size_t)gr * DD + gc] = (unsigned short)f2bf(v);
                    if (gc == 0) colp[gr] = v;   // exact fp32 col0 for layer-1 agg
                } else {
                    ((float*)out)[(size_t)gr * DD + gc] = v;
                }
            }
        }
    }
}

extern "C" void kernel_launch(void* const* d_in, const int* in_sizes, int n_in,
                              void* d_out, int out_size, void* d_ws, size_t ws_size,
                              hipStream_t stream) {
    const float* x1    = (const float*)d_in[0];
    const float* x2    = (const float*)d_in[1];
    const int*   adj12 = (const int*)d_in[2];
    const int*   adj21 = (const int*)d_in[3];
    const float* w1s0  = (const float*)d_in[4];
    const float* w1n0  = (const float*)d_in[5];
    const float* w2s0  = (const float*)d_in[6];
    const float* w2n0  = (const float*)d_in[7];
    const float* w1s1  = (const float*)d_in[8];
    const float* w1n1  = (const float*)d_in[9];
    const float* w2s1  = (const float*)d_in[10];
    const float* w2n1  = (const float*)d_in[11];

    char* ws = (char*)d_ws;
    size_t off = 0;
    auto alloc = [&](size_t bytes) { char* p = ws + off; off += (bytes + 15) & ~15ull; return p; };

    u64* bm21 = (u64*)alloc((size_t)NN * WPR * 8);                     // 12.8 MB
    u64* bm12 = (u64*)alloc((size_t)NN * WPR * 8);                     // 12.8 MB
    unsigned short* xb1 = (unsigned short*)alloc((size_t)NN * DD * 2); // 5.12 MB
    unsigned short* xb2 = (unsigned short*)alloc((size_t)NN * DD * 2);
    unsigned short* yb1 = (unsigned short*)alloc((size_t)NN * DD * 2);
    unsigned short* yb2 = (unsigned short*)alloc((size_t)NN * DD * 2);
    unsigned short* wb  = (unsigned short*)alloc(4ull * DD * DD * 2);  // 0.5 MB
    float* wsum = (float*)alloc(4ull * DD * 4);
    float* x1c  = (float*)alloc(COLPAD * 4);
    float* x2c  = (float*)alloc(COLPAD * 4);
    float* y1c  = (float*)alloc(COLPAD * 4);
    float* y2c  = (float*)alloc(COLPAD * 4);
    float* n1_0 = (float*)alloc(COLPAD * 4);
    float* n2_0 = (float*)alloc(COLPAD * 4);
    float* n1_1 = (float*)alloc(COLPAD * 4);
    float* n2_1 = (float*)alloc(COLPAD * 4);
    (void)ws_size; (void)in_sizes; (void)n_in; (void)out_size;

    float* out1 = (float*)d_out;
    float* out2 = out1 + (size_t)NN * DD;

    // 1. fused prep: x->bf16 (+col0), ws->bf16, wn row-sums
    prep<<<5512, 256, 0, stream>>>(x1, x2, xb1, xb2, x1c, x2c,
                                   w1s0, w2s0, w1s1, w2s1, wb,
                                   w1n0, w2n0, w1n1, w2n1, wsum);
    // 2. single adjacency pass (both matrices): bitmasks + layer-0 aggregates
    pack_agg2<<<2 * NN, 256, 0, stream>>>(adj21, adj12, x2c, x1c, bm21, bm12, n1_0, n2_0);
    // 3. layer 0 GEMMs (relu)
    gemm_mfma<0><<<dim3(2, 157, 2), 256, 0, stream>>>(
        xb1, wb + 0 * DD * DD, n1_0, wsum + 0 * DD, (void*)yb1, y1c,
        xb2, wb + 1 * DD * DD, n2_0, wsum + 1 * DD, (void*)yb2, y2c, NN);
    // 4. layer-1 aggregates from bitmasks (both matrices, 4 rows/wave)
    bit_agg4<<<1250, 256, 0, stream>>>(bm21, bm12, y2c, y1c, n1_1, n2_1);
    // 5. layer 1 GEMMs (identity) -> outputs
    gemm_mfma<1><<<dim3(2, 157, 2), 256, 0, stream>>>(
        yb1, wb + 2 * DD * DD, n1_1, wsum + 2 * DD, (void*)out1, (float*)nullptr,
        yb2, wb + 3 * DD * DD, n2_1, wsum + 3 * DD, (void*)out2, (float*)nullptr, NN);
}